// Round 11
// baseline (1452.747 us; speedup 1.0000x reference)
//
#include <hip/hip_runtime.h>

#define NNODES 25600
#define DEG 16
#define BGRAPHS 8
#define NPG (NNODES / BGRAPHS)   // 3200
#define FDIM 7
#define HDIM 300
#define LDIM 100
#define HP 320                   // padded H
#define NT1 20                   // GEMM1 N tiles
#define KS1 10                   // GEMM1 K steps
#define NT2 7                    // GEMM2 N tiles (112 cols, >=100 masked)
#define KS2 10                   // GEMM2 K steps
#define H0W 128                  // h0 fp16 padded width
#define SSTR 328                 // proj staging row stride (shorts)

typedef __attribute__((ext_vector_type(8))) _Float16 half8;
typedef __attribute__((ext_vector_type(2))) _Float16 half2v;
typedef __attribute__((ext_vector_type(4))) float floatx4;

__device__ __forceinline__ unsigned short f2h(float f) {   // fp32 -> fp16 bits (RNE)
    _Float16 h = (_Float16)f;
    return __builtin_bit_cast(unsigned short, h);
}

// packed fp32x2 -> fp16x2 (RTZ), re-typed to half2v
__device__ __forceinline__ half2v pkrtz(float a, float b) {
    return __builtin_bit_cast(half2v, __builtin_amdgcn_cvt_pkrtz(a, b));
}

union UV4H { uint4 v; half2v h[4]; };

// ---------------------------------------------------------------------------
// B-fragment packing, 4 consecutive j per thread (one 8B store):
// out[((nt*KS+ks)*64+lane)*8+j] = W[k][n]
// ---------------------------------------------------------------------------
__device__ __forceinline__ unsigned long long packB4(const float* W, int Kreal,
                                                     int Nreal, int KS, int rel)
{
    int j0 = rel & 7, lane = (rel >> 3) & 63, rem = rel >> 9;
    int ks = rem % KS, nt = rem / KS;
    int kb = ks * 32 + ((lane >> 4) << 3) + j0;
    int n = nt * 16 + (lane & 15);
    union { unsigned short us[4]; unsigned long long ll; } o;
#pragma unroll
    for (int j = 0; j < 4; ++j) {
        int k = kb + j;
        o.us[j] = (k < Kreal && n < Nreal) ? f2h(W[k * Nreal + n]) : (unsigned short)0;
    }
    return o.ll;
}

// proj effective weights Weff[k][n], n<320 = U part (W1a - W1b), n>=320 = V part
__device__ __forceinline__ unsigned long long packProjW4(const float* W1, int Ksub,
                                                         int KS, int rel)
{
    int j0 = rel & 7, lane = (rel >> 3) & 63, rem = rel >> 9;
    int ks = rem % KS, nt = rem / KS;
    int kb = ks * 32 + ((lane >> 4) << 3) + j0;
    int n = nt * 16 + (lane & 15);
    union { unsigned short us[4]; unsigned long long ll; } o;
#pragma unroll
    for (int j = 0; j < 4; ++j) {
        int k = kb + j;
        float v = 0.f;
        if (k < Ksub) {
            if (n < HP) { if (n < HDIM) v = W1[k * HDIM + n] - W1[(k + Ksub) * HDIM + n]; }
            else { int m = n - HP; if (m < HDIM) v = W1[(k + Ksub) * HDIM + m]; }
        }
        o.us[j] = f2h(v);
    }
    return o.ll;
}

#define S0 102400   // PB2_0
#define S1 102400   // PB2_1
#define S2 35840    // PB3_0
#define S3 35840    // PB3_1
#define S4 81920    // PW1 (40 nt x 4 ks)
#define S5 20480    // PW0 (40 nt x 1 ks)
// vectorized (4 shorts / thread) segment sizes:
#define P0 (S0/4)
#define P1 (S1/4)
#define P2 (S2/4)
#define P3 (S3/4)
#define P4 (S4/4)
#define P5 (S5/4)
#define PV (P0+P1+P2+P3+P4+P5)   // 94720
#define PBIAS 1920
#define PZERO 10001              // 40004 part floats (incl. done-counter) as float4
#define PACK_TOTAL (PV+PBIAS+PZERO)

__global__ __launch_bounds__(256) void pack_all_kernel(
    const float* __restrict__ l0_W1, const float* __restrict__ l0_b1,
    const float* __restrict__ l0_W2, const float* __restrict__ l0_b2,
    const float* __restrict__ l0_W3,
    const float* __restrict__ l1_W1, const float* __restrict__ l1_b1,
    const float* __restrict__ l1_W2, const float* __restrict__ l1_b2,
    const float* __restrict__ l1_W3,
    unsigned short* __restrict__ PB2_0, unsigned short* __restrict__ PB2_1,
    unsigned short* __restrict__ PB3_0, unsigned short* __restrict__ PB3_1,
    unsigned short* __restrict__ PW1,  unsigned short* __restrict__ PW0,
    float* __restrict__ b2p_0, float* __restrict__ b2p_1,
    float* __restrict__ bp1,   float* __restrict__ bp0,
    float* __restrict__ part)
{
    int idx = blockIdx.x * 256 + threadIdx.x;
    if (idx >= PACK_TOTAL) return;
    if (idx < P0) { ((unsigned long long*)PB2_0)[idx] = packB4(l0_W2, HDIM, HDIM, KS1, idx * 4); return; }
    idx -= P0;
    if (idx < P1) { ((unsigned long long*)PB2_1)[idx] = packB4(l1_W2, HDIM, HDIM, KS1, idx * 4); return; }
    idx -= P1;
    if (idx < P2) { ((unsigned long long*)PB3_0)[idx] = packB4(l0_W3, HDIM, LDIM, KS2, idx * 4); return; }
    idx -= P2;
    if (idx < P3) { ((unsigned long long*)PB3_1)[idx] = packB4(l1_W3, HDIM, LDIM, KS2, idx * 4); return; }
    idx -= P3;
    if (idx < P4) { ((unsigned long long*)PW1)[idx] = packProjW4(l1_W1, LDIM, 4, idx * 4); return; }
    idx -= P4;
    if (idx < P5) { ((unsigned long long*)PW0)[idx] = packProjW4(l0_W1, FDIM, 1, idx * 4); return; }
    idx -= P5;
    if (idx < 320)       { b2p_0[idx] = (idx < HDIM) ? l0_b2[idx] : 0.f; return; }
    if (idx < 640)       { int n = idx - 320; b2p_1[n] = (n < HDIM) ? l1_b2[n] : 0.f; return; }
    if (idx < 1280)      { int n = idx - 640; bp1[n] = (n < HDIM) ? l1_b1[n] : 0.f; return; }
    if (idx < 1920)      { int n = idx - 1280; bp0[n] = (n < HDIM) ? l0_b1[n] : 0.f; return; }
    ((floatx4*)part)[idx - 1920] = (floatx4){0.f, 0.f, 0.f, 0.f};   // re-zero partials + counter
}

// ---------------------------------------------------------------------------
// proj GEMM: A[64 rows] x Weff[K,320-col group] -> U or V fp16 (bias, no relu).
// Grid = 800: block handles (row strip = bid>>1, group g = bid&1). 2 barriers.
// ---------------------------------------------------------------------------
template<int KS, bool A_IS_X>
__global__ __launch_bounds__(256) void proj_gemm_kernel(
    const void* __restrict__ Asrc, const unsigned short* __restrict__ PW,
    const float* __restrict__ bp,
    unsigned short* __restrict__ Ub, unsigned short* __restrict__ Vb)
{
    __shared__ unsigned short As[4 * KS * 64 * 8];
    __shared__ unsigned short S[64 * SSTR];
    const int t = threadIdx.x;
    const int g = blockIdx.x & 1;
    const int row0 = (blockIdx.x >> 1) * 64;

    if constexpr (A_IS_X) {
        const float* x = (const float*)Asrc;
        int lane = t & 63, mt = t >> 6;
        int quad = lane >> 4;
        int grow = row0 + mt * 16 + (lane & 15);
        unsigned short oz[8];
#pragma unroll
        for (int j = 0; j < 8; ++j) {
            int k = quad * 8 + j;
            oz[j] = (k < FDIM) ? f2h(x[grow * FDIM + k]) : (unsigned short)0;
        }
        *(uint4*)(As + t * 8) = *(uint4*)oz;
    } else {
        const unsigned short* h = (const unsigned short*)Asrc;
#pragma unroll
        for (int i = 0; i < 4; ++i) {
            int s = t + 256 * i;
            int lane = s & 63;
            int ks = (s >> 6) % KS;
            int mt = s / (KS * 64);
            int grow = row0 + mt * 16 + (lane & 15);
            int k0 = ks * 32 + ((lane >> 4) << 3);
            *(uint4*)(As + s * 8) = *(const uint4*)(h + (size_t)grow * H0W + k0);
        }
    }
    __syncthreads();

    const int w = t >> 6, lane = t & 63, quad = lane >> 4, l15 = lane & 15;
    const int ntb = g * 20 + w * 5;

    floatx4 c[5][4];
#pragma unroll
    for (int i = 0; i < 5; ++i)
#pragma unroll
        for (int mt = 0; mt < 4; ++mt) c[i][mt] = (floatx4){0.f, 0.f, 0.f, 0.f};
#pragma unroll
    for (int ks = 0; ks < KS; ++ks) {
        half8 a[4];
#pragma unroll
        for (int mt = 0; mt < 4; ++mt)
            a[mt] = *(const half8*)(As + ((mt * KS + ks) * 64 + lane) * 8);
#pragma unroll
        for (int i = 0; i < 5; ++i) {
            half8 b = *(const half8*)(PW + (size_t)(((ntb + i) * KS + ks) * 64 + lane) * 8);
#pragma unroll
            for (int mt = 0; mt < 4; ++mt)
                c[i][mt] = __builtin_amdgcn_mfma_f32_16x16x32_f16(a[mt], b, c[i][mt], 0, 0, 0);
        }
    }
#pragma unroll
    for (int i = 0; i < 5; ++i) {
        int colp = (w * 5 + i) * 16 + l15;        // 0..319 group-local
        float bb = bp[g * 320 + colp];
#pragma unroll
        for (int mt = 0; mt < 4; ++mt) {
#pragma unroll
            for (int r = 0; r < 4; ++r) {
                int row = mt * 16 + quad * 4 + r;
                S[row * SSTR + colp] = f2h(c[i][mt][r] + bb);
            }
        }
    }
    __syncthreads();
    unsigned short* dst = g ? Vb : Ub;
#pragma unroll
    for (int it = 0; it < 10; ++it) {
        int s = t + 256 * it;
        int row = s / 40, c4 = s - row * 40;
        uint4 v = *(const uint4*)(S + row * SSTR + c4 * 8);
        *(uint4*)(dst + (size_t)(row0 + row) * HP + c4 * 8) = v;
    }
}

// ---------------------------------------------------------------------------
// Fused edge MLP + segment-max. Block = 4 nodes (M=64), 512 threads / 8 waves.
// fp16 pipeline. Single 40 KB LDS buffer, 3 barriers.
//   Z1 build, remapped: thread (w,lane) owns mt=w>>1 (const), ks=(w&1)*5+q.
//   GEMM1 (operand-swapped), 20 tiles {3,3,3,3,2,2,2,2}; weight frags
//     software-pipelined (ping-pong, distance 1; first frag hoisted above
//     the Z1 barrier). setprio kept (null but harmless, r10).
//   GEMM2: wave w<7 owns 1 ntile; same b-frag pipeline.
//   OUT_HALF=true : store h0 rows (fp16, padded to 128).
//   OUT_HALF=false: fused graph pooling -> slice atomics; LAST block (device
//     counter, release/acquire threadfence) runs the head MLP in-kernel
//     (replaces final_kernel; Zs reused as fp32 scratch).
// ---------------------------------------------------------------------------
template<bool OUT_HALF>
__global__ __launch_bounds__(512, 4) void edge_mfma_kernel(
    const unsigned short* __restrict__ Ub,
    const unsigned short* __restrict__ Vb,
    const int* __restrict__ src,
    const unsigned short* __restrict__ PB2, const float* __restrict__ b2p,
    const unsigned short* __restrict__ PB3, const float* __restrict__ b3,
    void* __restrict__ hout,
    int* counter,
    const float* __restrict__ lW1, const float* __restrict__ lb1,
    const float* __restrict__ lW2, const float* __restrict__ lb2,
    const float* __restrict__ lW3, const float* __restrict__ lb3,
    float* __restrict__ out)
{
    __shared__ unsigned short Zs[4 * KS1 * 64 * 8];   // 40960 B, Z1 then Z2
    __shared__ int lastFlag;

    const int t = threadIdx.x;
    const int node0 = blockIdx.x * 4;
    const int lane = t & 63;
    const int w = t >> 6;                 // 0..7
    const int quad = lane >> 4;
    const int l15 = lane & 15;
    const int slane = lane ^ ((lane & 0x30) >> 3);   // sigma(lane) for Z1 reads

    // Z1-build lane mapping (64B-coalesced gather + swizzled LDS dest)
    const int row16 = lane >> 2;          // 0..15
    const int part  = lane & 3;           // 0..3
    const int fl    = row16 + 16 * part;  // A-frag lane
    const int phys  = fl ^ (part << 1);   // sigma(fl)

    const half2v hzero = {(_Float16)0.f, (_Float16)0.f};

    // ---- Z1 build: thread (w,lane) -> mt=w>>1, ks=(w&1)*5+q, q=0..4 ----
    {
        const int mtw = w >> 1;
        const int ks0 = (w & 1) * 5;
        const int srcn = src[node0 * 16 + mtw * 16 + row16];
        const unsigned short* up = Ub + (size_t)(node0 + mtw) * HP + ks0 * 32 + part * 8;
        const unsigned short* vp = Vb + (size_t)srcn * HP + ks0 * 32 + part * 8;
        unsigned short* zp = Zs + ((mtw * KS1 + ks0) * 64 + phys) * 8;
#pragma unroll
        for (int q = 0; q < 5; ++q) {
            UV4H ud, vd, o;
            ud.v = *(const uint4*)(up + q * 32);
            vd.v = *(const uint4*)(vp + q * 32);
#pragma unroll
            for (int d = 0; d < 4; ++d) {
                half2v s2 = ud.h[d] + vd.h[d];                       // v_pk_add_f16
                o.h[d] = __builtin_elementwise_max(s2, hzero);       // v_pk_max_f16
            }
            *(uint4*)(zp + q * 512) = o.v;
        }
    }

    // ---- GEMM1 setup + first weight fragment hoisted above the barrier ----
    const int cnt1  = (w < 4) ? 3 : 2;
    const int base1 = (w < 4) ? 3 * w : 12 + 2 * (w - 4);
    const unsigned short* pb = PB2 + ((size_t)base1 * KS1 * 64 + lane) * 8;
    // strides in shorts: ks slab = 512, tile = KS1*512

    auto ld_wa = [&](half8 (&buf)[3], int kss) {
        buf[0] = *(const half8*)(pb + kss * 512);
        buf[1] = *(const half8*)(pb + KS1 * 512 + kss * 512);
        if (cnt1 > 2) buf[2] = *(const half8*)(pb + 2 * KS1 * 512 + kss * 512);
    };
    auto ld_zb = [&](half8 (&zb)[4], int ks) {
#pragma unroll
        for (int mt = 0; mt < 4; ++mt)
            zb[mt] = *(const half8*)(Zs + ((mt * KS1 + ks) * 64 + slane) * 8);
    };

    floatx4 c1[3][4];
#pragma unroll
    for (int i = 0; i < 3; ++i)
#pragma unroll
        for (int mt = 0; mt < 4; ++mt) c1[i][mt] = (floatx4){0.f, 0.f, 0.f, 0.f};

    auto mm3 = [&](half8 (&wa)[3], half8 (&zb)[4]) {
#pragma unroll
        for (int i = 0; i < 3; ++i) {
            if (i < cnt1) {
#pragma unroll
                for (int mt = 0; mt < 4; ++mt)
                    c1[i][mt] = __builtin_amdgcn_mfma_f32_16x16x32_f16(wa[i], zb[mt], c1[i][mt], 0, 0, 0);
            }
        }
    };

    half8 waA[3], waB[3];
    ld_wa(waA, 0);                 // overlaps the Z1 gather (read-only global)
    __syncthreads();

    // ---- GEMM1: ping-pong prefetch, distance 1, elevated priority ----
    __builtin_amdgcn_s_setprio(1);
#pragma unroll 1
    for (int ks = 0; ks < KS1; ks += 2) {
        half8 zb[4];
        ld_zb(zb, ks);
        ld_wa(waB, ks + 1);        // ks+1 <= KS1-1 (KS1 even)
        mm3(waA, zb);
        ld_zb(zb, ks + 1);
        if (ks + 2 < KS1) ld_wa(waA, ks + 2);
        mm3(waB, zb);
    }
    __builtin_amdgcn_s_setprio(0);
    __syncthreads();   // all waves done reading Z1

    // ---- Z2 scatter (packed): lane holds rows n=B*16+quad*4+{0..3} of col m ----
    // Z2[m][n] -> A-frag slot: ks=n>>5, sub-lane hi=(n&31)>>3, j=n&7.
#pragma unroll
    for (int i = 0; i < 3; ++i) {
        if (i < cnt1) {
            int B = base1 + i;                       // ntile 0..19
            const floatx4 bb = *(const floatx4*)(b2p + B * 16 + quad * 4);
            half2v hb0 = pkrtz(bb[0], bb[1]);
            half2v hb1 = pkrtz(bb[2], bb[3]);
            int ks = B >> 1;
            int khi = (2 * B + (quad >> 1)) & 3;
            int jo = (quad & 1) * 4;
#pragma unroll
            for (int mt = 0; mt < 4; ++mt) {
                half2v c01 = pkrtz(c1[i][mt][0], c1[i][mt][1]);
                half2v c23 = pkrtz(c1[i][mt][2], c1[i][mt][3]);
                union { half2v h[2]; unsigned long long ll; } o;
                o.h[0] = __builtin_elementwise_max(c01 + hb0, hzero);
                o.h[1] = __builtin_elementwise_max(c23 + hb1, hzero);
                *(unsigned long long*)(Zs + ((mt * KS1 + ks) * 64 + l15 + 16 * khi) * 8 + jo) = o.ll;
            }
        }
    }

    // ---- GEMM2 first weight fragment hoisted above the barrier ----
    const unsigned short* pb3 = PB3 + ((size_t)w * KS2 * 64 + lane) * 8;
    half8 bA, bB;
    if (w < NT2) bA = *(const half8*)(pb3);
    __syncthreads();

    // ---- GEMM2: wave w<7 owns ntile w, all 4 mt; b-frag pipelined ----
    floatx4 c2[4];
#pragma unroll
    for (int mt = 0; mt < 4; ++mt) c2[mt] = (floatx4){0.f, 0.f, 0.f, 0.f};
    if (w < NT2) {
        __builtin_amdgcn_s_setprio(1);
#pragma unroll 1
        for (int ks = 0; ks < KS2; ks += 2) {
            half8 a[4];
#pragma unroll
            for (int mt = 0; mt < 4; ++mt)
                a[mt] = *(const half8*)(Zs + ((mt * KS2 + ks) * 64 + lane) * 8);
            bB = *(const half8*)(pb3 + (ks + 1) * 512);
#pragma unroll
            for (int mt = 0; mt < 4; ++mt)
                c2[mt] = __builtin_amdgcn_mfma_f32_16x16x32_f16(a[mt], bA, c2[mt], 0, 0, 0);
#pragma unroll
            for (int mt = 0; mt < 4; ++mt)
                a[mt] = *(const half8*)(Zs + ((mt * KS2 + ks + 1) * 64 + lane) * 8);
            if (ks + 2 < KS2) bA = *(const half8*)(pb3 + (ks + 2) * 512);
#pragma unroll
            for (int mt = 0; mt < 4; ++mt)
                c2[mt] = __builtin_amdgcn_mfma_f32_16x16x32_f16(a[mt], bB, c2[mt], 0, 0, 0);
        }
        __builtin_amdgcn_s_setprio(0);
    }

    // ---- epilogue: max over 16 edge rows, +b3, relu ----
    if constexpr (OUT_HALF) {
#pragma unroll
        for (int mt = 0; mt < 4; ++mt) {
            int node = node0 + mt;
            if (w < NT2) {
                int col = w * 16 + l15;
                floatx4 a = c2[mt];
                float mx = fmaxf(fmaxf(a[0], a[1]), fmaxf(a[2], a[3]));
                mx = fmaxf(mx, __shfl_xor(mx, 16, 64));
                mx = fmaxf(mx, __shfl_xor(mx, 32, 64));
                if (quad == 0) {
                    unsigned short val = 0;
                    if (col < LDIM) val = f2h(fmaxf(mx + b3[col], 0.f));
                    ((unsigned short*)hout)[(size_t)node * H0W + col] = val;
                }
            }
            if (w == 7 && quad == 0)     // pad cols 112..127
                ((unsigned short*)hout)[(size_t)node * H0W + 112 + l15] = 0;
        }
    } else {
        // fused graph pooling into 25-slice partials
        float* partf = (float*)hout;
        if (w < NT2) {
            int col = w * 16 + l15;
            float bv = (col < LDIM) ? b3[col] : 0.f;
            float s4 = 0.f, m4 = 0.f;
#pragma unroll
            for (int mt = 0; mt < 4; ++mt) {
                floatx4 a = c2[mt];
                float mx = fmaxf(fmaxf(a[0], a[1]), fmaxf(a[2], a[3]));
                mx = fmaxf(mx, __shfl_xor(mx, 16, 64));
                mx = fmaxf(mx, __shfl_xor(mx, 32, 64));
                float v = fmaxf(mx + bv, 0.f);
                s4 += v;
                m4 = fmaxf(m4, v);
            }
            if (quad == 0 && col < LDIM) {
                int slice = blockIdx.x >> 5;          // = g*25 + sl  (32 blocks/slice)
                float* ps = partf + (size_t)slice * 200;
                atomicAdd(ps + col, s4);
                atomicMax((int*)(ps + 100 + col), __float_as_int(m4));
            }
        }

        // ---- last-block fused head MLP (replaces final_kernel) ----
        __threadfence();                          // release: pool atomics before signal
        __syncthreads();                          // whole block's atomics issued
        if (t == 0) lastFlag = (atomicAdd(counter, 1) == (NNODES / 4 - 1));
        __syncthreads();
        if (lastFlag) {
            __threadfence();                      // acquire: see all blocks' partials
            float* P  = (float*)Zs;               // [8][300] fp32 scratch in LDS
            float* T1 = P + BGRAPHS * 300;        // [8][100]
            float* T2 = T1 + BGRAPHS * 100;       // [8][100]  (total 16 KB < 40 KB)
            for (int i = t; i < BGRAPHS * LDIM; i += 512) {
                int gg = i / LDIM, f = i - (i / LDIM) * LDIM;
                float s = 0.f, mx = 0.f;
                for (int sl = 0; sl < 25; ++sl) {
                    s += partf[(size_t)(gg * 25 + sl) * 200 + f];
                    mx = fmaxf(mx, partf[(size_t)(gg * 25 + sl) * 200 + 100 + f]);
                }
                P[gg * 300 + f] = s;
                P[gg * 300 + LDIM + f] = s * (1.0f / NPG);
                P[gg * 300 + 2 * LDIM + f] = mx;
            }
            __syncthreads();
            for (int i = t; i < BGRAPHS * LDIM; i += 512) {
                int gg = i / LDIM, c = i - (i / LDIM) * LDIM;
                float a = lb1[c];
                for (int k = 0; k < 3 * LDIM; ++k) a = fmaf(P[gg * 300 + k], lW1[k * LDIM + c], a);
                T1[gg * 100 + c] = fmaxf(a, 0.f);
            }
            __syncthreads();
            for (int i = t; i < BGRAPHS * LDIM; i += 512) {
                int gg = i / LDIM, c = i - (i / LDIM) * LDIM;
                float a = lb2[c];
                for (int k = 0; k < LDIM; ++k) a = fmaf(T1[gg * 100 + k], lW2[k * LDIM + c], a);
                T2[gg * 100 + c] = fmaxf(a, 0.f);
            }
            __syncthreads();
            if (t < BGRAPHS) {
                float a = lb3[0];
                for (int k = 0; k < LDIM; ++k) a = fmaf(T2[t * 100 + k], lW3[k], a);
                out[t] = a;
            }
        }
    }
}

// ---------------------------------------------------------------------------
extern "C" void kernel_launch(void* const* d_in, const int* in_sizes, int n_in,
                              void* d_out, int out_size, void* d_ws, size_t ws_size,
                              hipStream_t stream)
{
    const float* x      = (const float*)d_in[0];
    const int*   src    = (const int*)d_in[1];
    const float* l0_W1  = (const float*)d_in[3];
    const float* l0_b1  = (const float*)d_in[4];
    const float* l0_W2  = (const float*)d_in[5];
    const float* l0_b2  = (const float*)d_in[6];
    const float* l0_W3  = (const float*)d_in[7];
    const float* l0_b3  = (const float*)d_in[8];
    const float* l1_W1  = (const float*)d_in[9];
    const float* l1_b1  = (const float*)d_in[10];
    const float* l1_W2  = (const float*)d_in[11];
    const float* l1_b2  = (const float*)d_in[12];
    const float* l1_W3  = (const float*)d_in[13];
    const float* l1_b3  = (const float*)d_in[14];
    const float* lin_W1 = (const float*)d_in[15];
    const float* lin_b1 = (const float*)d_in[16];
    const float* lin_W2 = (const float*)d_in[17];
    const float* lin_b2 = (const float*)d_in[18];
    const float* lin_W3 = (const float*)d_in[19];
    const float* lin_b3 = (const float*)d_in[20];
    float* out = (float*)d_out;

    char* p = (char*)d_ws;
    unsigned short* Ubuf  = (unsigned short*)p;  p += (size_t)NNODES * HP * 2;      // 16.38 MB
    unsigned short* Vbuf  = (unsigned short*)p;  p += (size_t)NNODES * HP * 2;      // 16.38 MB
    unsigned short* h0b   = (unsigned short*)p;  p += (size_t)NNODES * H0W * 2;     // 6.55 MB
    unsigned short* PB2_0 = (unsigned short*)p;  p += (size_t)S0 * 2;
    unsigned short* PB2_1 = (unsigned short*)p;  p += (size_t)S1 * 2;
    unsigned short* PB3_0 = (unsigned short*)p;  p += (size_t)S2 * 2;
    unsigned short* PB3_1 = (unsigned short*)p;  p += (size_t)S3 * 2;
    unsigned short* PW1   = (unsigned short*)p;  p += (size_t)S4 * 2;
    unsigned short* PW0   = (unsigned short*)p;  p += (size_t)S5 * 2;
    float* b2p_0          = (float*)p;           p += HP * 4;
    float* b2p_1          = (float*)p;           p += HP * 4;
    float* bp1            = (float*)p;           p += 640 * 4;
    float* bp0            = (float*)p;           p += 640 * 4;
    float* part           = (float*)p;           p += (size_t)40004 * 4;            // partials + counter
    int* counter          = (int*)(part + 40000);

    pack_all_kernel<<<(PACK_TOTAL + 255) / 256, 256, 0, stream>>>(
        l0_W1, l0_b1, l0_W2, l0_b2, l0_W3,
        l1_W1, l1_b1, l1_W2, l1_b2, l1_W3,
        PB2_0, PB2_1, PB3_0, PB3_1, PW1, PW0, b2p_0, b2p_1, bp1, bp0, part);

    // layer 0
    proj_gemm_kernel<1, true><<<NNODES / 32, 256, 0, stream>>>(x, PW0, bp0, Ubuf, Vbuf);
    edge_mfma_kernel<true><<<NNODES / 4, 512, 0, stream>>>(
        Ubuf, Vbuf, src, PB2_0, b2p_0, PB3_0, l0_b3, h0b,
        nullptr, nullptr, nullptr, nullptr, nullptr, nullptr, nullptr, nullptr);
    // layer 1 (pooling fused via slice atomics; last block runs the head MLP)
    proj_gemm_kernel<4, false><<<NNODES / 32, 256, 0, stream>>>(h0b, PW1, bp1, Ubuf, Vbuf);
    edge_mfma_kernel<false><<<NNODES / 4, 512, 0, stream>>>(
        Ubuf, Vbuf, src, PB2_1, b2p_1, PB3_1, l1_b3, part,
        counter, lin_W1, lin_b1, lin_W2, lin_b2, lin_W3, lin_b3, out);
}

// Round 12
// 399.331 us; speedup vs baseline: 3.6380x; 3.6380x over previous
//
#include <hip/hip_runtime.h>

#define NNODES 25600
#define DEG 16
#define BGRAPHS 8
#define NPG (NNODES / BGRAPHS)   // 3200
#define FDIM 7
#define HDIM 300
#define LDIM 100
#define HP 320                   // padded H
#define NT1 20                   // GEMM1 N tiles
#define KS1 10                   // GEMM1 K steps
#define NT2 7                    // GEMM2 N tiles (112 cols, >=100 masked)
#define KS2 10                   // GEMM2 K steps
#define H0W 128                  // h0 fp16 padded width
#define SSTR 328                 // proj staging row stride (shorts)

typedef __attribute__((ext_vector_type(8))) _Float16 half8;
typedef __attribute__((ext_vector_type(2))) _Float16 half2v;
typedef __attribute__((ext_vector_type(4))) float floatx4;

__device__ __forceinline__ unsigned short f2h(float f) {   // fp32 -> fp16 bits (RNE)
    _Float16 h = (_Float16)f;
    return __builtin_bit_cast(unsigned short, h);
}

// packed fp32x2 -> fp16x2 (RTZ), re-typed to half2v
__device__ __forceinline__ half2v pkrtz(float a, float b) {
    return __builtin_bit_cast(half2v, __builtin_amdgcn_cvt_pkrtz(a, b));
}

union UV4H { uint4 v; half2v h[4]; };

// ---------------------------------------------------------------------------
// B-fragment packing, 4 consecutive j per thread (one 8B store):
// out[((nt*KS+ks)*64+lane)*8+j] = W[k][n]
// ---------------------------------------------------------------------------
__device__ __forceinline__ unsigned long long packB4(const float* W, int Kreal,
                                                     int Nreal, int KS, int rel)
{
    int j0 = rel & 7, lane = (rel >> 3) & 63, rem = rel >> 9;
    int ks = rem % KS, nt = rem / KS;
    int kb = ks * 32 + ((lane >> 4) << 3) + j0;
    int n = nt * 16 + (lane & 15);
    union { unsigned short us[4]; unsigned long long ll; } o;
#pragma unroll
    for (int j = 0; j < 4; ++j) {
        int k = kb + j;
        o.us[j] = (k < Kreal && n < Nreal) ? f2h(W[k * Nreal + n]) : (unsigned short)0;
    }
    return o.ll;
}

// proj effective weights Weff[k][n], n<320 = U part (W1a - W1b), n>=320 = V part
__device__ __forceinline__ unsigned long long packProjW4(const float* W1, int Ksub,
                                                         int KS, int rel)
{
    int j0 = rel & 7, lane = (rel >> 3) & 63, rem = rel >> 9;
    int ks = rem % KS, nt = rem / KS;
    int kb = ks * 32 + ((lane >> 4) << 3) + j0;
    int n = nt * 16 + (lane & 15);
    union { unsigned short us[4]; unsigned long long ll; } o;
#pragma unroll
    for (int j = 0; j < 4; ++j) {
        int k = kb + j;
        float v = 0.f;
        if (k < Ksub) {
            if (n < HP) { if (n < HDIM) v = W1[k * HDIM + n] - W1[(k + Ksub) * HDIM + n]; }
            else { int m = n - HP; if (m < HDIM) v = W1[(k + Ksub) * HDIM + m]; }
        }
        o.us[j] = f2h(v);
    }
    return o.ll;
}

#define S0 102400   // PB2_0
#define S1 102400   // PB2_1
#define S2 35840    // PB3_0
#define S3 35840    // PB3_1
#define S4 81920    // PW1 (40 nt x 4 ks)
#define S5 20480    // PW0 (40 nt x 1 ks)
// vectorized (4 shorts / thread) segment sizes:
#define P0 (S0/4)
#define P1 (S1/4)
#define P2 (S2/4)
#define P3 (S3/4)
#define P4 (S4/4)
#define P5 (S5/4)
#define PV (P0+P1+P2+P3+P4+P5)   // 94720
#define PBIAS 1920
#define PZERO 10001              // 40004 part floats (incl. done-counter) as float4
#define PACK_TOTAL (PV+PBIAS+PZERO)

__global__ __launch_bounds__(256) void pack_all_kernel(
    const float* __restrict__ l0_W1, const float* __restrict__ l0_b1,
    const float* __restrict__ l0_W2, const float* __restrict__ l0_b2,
    const float* __restrict__ l0_W3,
    const float* __restrict__ l1_W1, const float* __restrict__ l1_b1,
    const float* __restrict__ l1_W2, const float* __restrict__ l1_b2,
    const float* __restrict__ l1_W3,
    unsigned short* __restrict__ PB2_0, unsigned short* __restrict__ PB2_1,
    unsigned short* __restrict__ PB3_0, unsigned short* __restrict__ PB3_1,
    unsigned short* __restrict__ PW1,  unsigned short* __restrict__ PW0,
    float* __restrict__ b2p_0, float* __restrict__ b2p_1,
    float* __restrict__ bp1,   float* __restrict__ bp0,
    float* __restrict__ part)
{
    int idx = blockIdx.x * 256 + threadIdx.x;
    if (idx >= PACK_TOTAL) return;
    if (idx < P0) { ((unsigned long long*)PB2_0)[idx] = packB4(l0_W2, HDIM, HDIM, KS1, idx * 4); return; }
    idx -= P0;
    if (idx < P1) { ((unsigned long long*)PB2_1)[idx] = packB4(l1_W2, HDIM, HDIM, KS1, idx * 4); return; }
    idx -= P1;
    if (idx < P2) { ((unsigned long long*)PB3_0)[idx] = packB4(l0_W3, HDIM, LDIM, KS2, idx * 4); return; }
    idx -= P2;
    if (idx < P3) { ((unsigned long long*)PB3_1)[idx] = packB4(l1_W3, HDIM, LDIM, KS2, idx * 4); return; }
    idx -= P3;
    if (idx < P4) { ((unsigned long long*)PW1)[idx] = packProjW4(l1_W1, LDIM, 4, idx * 4); return; }
    idx -= P4;
    if (idx < P5) { ((unsigned long long*)PW0)[idx] = packProjW4(l0_W1, FDIM, 1, idx * 4); return; }
    idx -= P5;
    if (idx < 320)       { b2p_0[idx] = (idx < HDIM) ? l0_b2[idx] : 0.f; return; }
    if (idx < 640)       { int n = idx - 320; b2p_1[n] = (n < HDIM) ? l1_b2[n] : 0.f; return; }
    if (idx < 1280)      { int n = idx - 640; bp1[n] = (n < HDIM) ? l1_b1[n] : 0.f; return; }
    if (idx < 1920)      { int n = idx - 1280; bp0[n] = (n < HDIM) ? l0_b1[n] : 0.f; return; }
    ((floatx4*)part)[idx - 1920] = (floatx4){0.f, 0.f, 0.f, 0.f};   // re-zero partials + counter
}

// ---------------------------------------------------------------------------
// proj GEMM: A[64 rows] x Weff[K,320-col group] -> U or V fp16 (bias, no relu).
// Grid = 800: block handles (row strip = bid>>1, group g = bid&1). 2 barriers.
// ---------------------------------------------------------------------------
template<int KS, bool A_IS_X>
__global__ __launch_bounds__(256) void proj_gemm_kernel(
    const void* __restrict__ Asrc, const unsigned short* __restrict__ PW,
    const float* __restrict__ bp,
    unsigned short* __restrict__ Ub, unsigned short* __restrict__ Vb)
{
    __shared__ unsigned short As[4 * KS * 64 * 8];
    __shared__ unsigned short S[64 * SSTR];
    const int t = threadIdx.x;
    const int g = blockIdx.x & 1;
    const int row0 = (blockIdx.x >> 1) * 64;

    if constexpr (A_IS_X) {
        const float* x = (const float*)Asrc;
        int lane = t & 63, mt = t >> 6;
        int quad = lane >> 4;
        int grow = row0 + mt * 16 + (lane & 15);
        unsigned short oz[8];
#pragma unroll
        for (int j = 0; j < 8; ++j) {
            int k = quad * 8 + j;
            oz[j] = (k < FDIM) ? f2h(x[grow * FDIM + k]) : (unsigned short)0;
        }
        *(uint4*)(As + t * 8) = *(uint4*)oz;
    } else {
        const unsigned short* h = (const unsigned short*)Asrc;
#pragma unroll
        for (int i = 0; i < 4; ++i) {
            int s = t + 256 * i;
            int lane = s & 63;
            int ks = (s >> 6) % KS;
            int mt = s / (KS * 64);
            int grow = row0 + mt * 16 + (lane & 15);
            int k0 = ks * 32 + ((lane >> 4) << 3);
            *(uint4*)(As + s * 8) = *(const uint4*)(h + (size_t)grow * H0W + k0);
        }
    }
    __syncthreads();

    const int w = t >> 6, lane = t & 63, quad = lane >> 4, l15 = lane & 15;
    const int ntb = g * 20 + w * 5;

    floatx4 c[5][4];
#pragma unroll
    for (int i = 0; i < 5; ++i)
#pragma unroll
        for (int mt = 0; mt < 4; ++mt) c[i][mt] = (floatx4){0.f, 0.f, 0.f, 0.f};
#pragma unroll
    for (int ks = 0; ks < KS; ++ks) {
        half8 a[4];
#pragma unroll
        for (int mt = 0; mt < 4; ++mt)
            a[mt] = *(const half8*)(As + ((mt * KS + ks) * 64 + lane) * 8);
#pragma unroll
        for (int i = 0; i < 5; ++i) {
            half8 b = *(const half8*)(PW + (size_t)(((ntb + i) * KS + ks) * 64 + lane) * 8);
#pragma unroll
            for (int mt = 0; mt < 4; ++mt)
                c[i][mt] = __builtin_amdgcn_mfma_f32_16x16x32_f16(a[mt], b, c[i][mt], 0, 0, 0);
        }
    }
#pragma unroll
    for (int i = 0; i < 5; ++i) {
        int colp = (w * 5 + i) * 16 + l15;        // 0..319 group-local
        float bb = bp[g * 320 + colp];
#pragma unroll
        for (int mt = 0; mt < 4; ++mt) {
#pragma unroll
            for (int r = 0; r < 4; ++r) {
                int row = mt * 16 + quad * 4 + r;
                S[row * SSTR + colp] = f2h(c[i][mt][r] + bb);
            }
        }
    }
    __syncthreads();
    unsigned short* dst = g ? Vb : Ub;
#pragma unroll
    for (int it = 0; it < 10; ++it) {
        int s = t + 256 * it;
        int row = s / 40, c4 = s - row * 40;
        uint4 v = *(const uint4*)(S + row * SSTR + c4 * 8);
        *(uint4*)(dst + (size_t)(row0 + row) * HP + c4 * 8) = v;
    }
}

// ---------------------------------------------------------------------------
// Fused edge MLP + segment-max. Block = 4 nodes (M=64), 512 threads / 8 waves.
// fp16 pipeline. Single 40 KB LDS buffer, 3 barriers.
//   Z1 build, remapped: thread (w,lane) owns mt=w>>1 (const), ks=(w&1)*5+q.
//   GEMM1 (operand-swapped), 20 tiles {3,3,3,3,2,2,2,2}; weight frags
//     software-pipelined (ping-pong, distance 1; first frag hoisted above
//     the Z1 barrier).
//   GEMM2: wave w<7 owns 1 ntile; same b-frag pipeline.
//   OUT_HALF=true : store h0 rows (fp16, padded to 128).
//   OUT_HALF=false: fused graph pooling -> slice atomics; LAST block runs the
//     head MLP in-kernel. CHEAP fences (r11 lesson: per-block __threadfence
//     = buffer_wbl2 per wave = 9x slowdown): release = s_waitcnt vmcnt(0)
//     (atomics are performed at device coherence point, never dirty in local
//     L2 -> no writeback needed); acquire = one full __threadfence in the
//     single winning block.
// ---------------------------------------------------------------------------
template<bool OUT_HALF>
__global__ __launch_bounds__(512, 4) void edge_mfma_kernel(
    const unsigned short* __restrict__ Ub,
    const unsigned short* __restrict__ Vb,
    const int* __restrict__ src,
    const unsigned short* __restrict__ PB2, const float* __restrict__ b2p,
    const unsigned short* __restrict__ PB3, const float* __restrict__ b3,
    void* __restrict__ hout,
    int* counter,
    const float* __restrict__ lW1, const float* __restrict__ lb1,
    const float* __restrict__ lW2, const float* __restrict__ lb2,
    const float* __restrict__ lW3, const float* __restrict__ lb3,
    float* __restrict__ out)
{
    __shared__ unsigned short Zs[4 * KS1 * 64 * 8];   // 40960 B, Z1 then Z2
    __shared__ int lastFlag;

    const int t = threadIdx.x;
    const int node0 = blockIdx.x * 4;
    const int lane = t & 63;
    const int w = t >> 6;                 // 0..7
    const int quad = lane >> 4;
    const int l15 = lane & 15;
    const int slane = lane ^ ((lane & 0x30) >> 3);   // sigma(lane) for Z1 reads

    // Z1-build lane mapping (64B-coalesced gather + swizzled LDS dest)
    const int row16 = lane >> 2;          // 0..15
    const int part  = lane & 3;           // 0..3
    const int fl    = row16 + 16 * part;  // A-frag lane
    const int phys  = fl ^ (part << 1);   // sigma(fl)

    const half2v hzero = {(_Float16)0.f, (_Float16)0.f};

    // ---- Z1 build: thread (w,lane) -> mt=w>>1, ks=(w&1)*5+q, q=0..4 ----
    {
        const int mtw = w >> 1;
        const int ks0 = (w & 1) * 5;
        const int srcn = src[node0 * 16 + mtw * 16 + row16];
        const unsigned short* up = Ub + (size_t)(node0 + mtw) * HP + ks0 * 32 + part * 8;
        const unsigned short* vp = Vb + (size_t)srcn * HP + ks0 * 32 + part * 8;
        unsigned short* zp = Zs + ((mtw * KS1 + ks0) * 64 + phys) * 8;
#pragma unroll
        for (int q = 0; q < 5; ++q) {
            UV4H ud, vd, o;
            ud.v = *(const uint4*)(up + q * 32);
            vd.v = *(const uint4*)(vp + q * 32);
#pragma unroll
            for (int d = 0; d < 4; ++d) {
                half2v s2 = ud.h[d] + vd.h[d];                       // v_pk_add_f16
                o.h[d] = __builtin_elementwise_max(s2, hzero);       // v_pk_max_f16
            }
            *(uint4*)(zp + q * 512) = o.v;
        }
    }

    // ---- GEMM1 setup + first weight fragment hoisted above the barrier ----
    const int cnt1  = (w < 4) ? 3 : 2;
    const int base1 = (w < 4) ? 3 * w : 12 + 2 * (w - 4);
    const unsigned short* pb = PB2 + ((size_t)base1 * KS1 * 64 + lane) * 8;
    // strides in shorts: ks slab = 512, tile = KS1*512

    auto ld_wa = [&](half8 (&buf)[3], int kss) {
        buf[0] = *(const half8*)(pb + kss * 512);
        buf[1] = *(const half8*)(pb + KS1 * 512 + kss * 512);
        if (cnt1 > 2) buf[2] = *(const half8*)(pb + 2 * KS1 * 512 + kss * 512);
    };
    auto ld_zb = [&](half8 (&zb)[4], int ks) {
#pragma unroll
        for (int mt = 0; mt < 4; ++mt)
            zb[mt] = *(const half8*)(Zs + ((mt * KS1 + ks) * 64 + slane) * 8);
    };

    floatx4 c1[3][4];
#pragma unroll
    for (int i = 0; i < 3; ++i)
#pragma unroll
        for (int mt = 0; mt < 4; ++mt) c1[i][mt] = (floatx4){0.f, 0.f, 0.f, 0.f};

    auto mm3 = [&](half8 (&wa)[3], half8 (&zb)[4]) {
#pragma unroll
        for (int i = 0; i < 3; ++i) {
            if (i < cnt1) {
#pragma unroll
                for (int mt = 0; mt < 4; ++mt)
                    c1[i][mt] = __builtin_amdgcn_mfma_f32_16x16x32_f16(wa[i], zb[mt], c1[i][mt], 0, 0, 0);
            }
        }
    };

    half8 waA[3], waB[3];
    ld_wa(waA, 0);                 // overlaps the Z1 gather (read-only global)
    __syncthreads();

    // ---- GEMM1: ping-pong prefetch, distance 1, elevated priority ----
    __builtin_amdgcn_s_setprio(1);
#pragma unroll 1
    for (int ks = 0; ks < KS1; ks += 2) {
        half8 zb[4];
        ld_zb(zb, ks);
        ld_wa(waB, ks + 1);        // ks+1 <= KS1-1 (KS1 even)
        mm3(waA, zb);
        ld_zb(zb, ks + 1);
        if (ks + 2 < KS1) ld_wa(waA, ks + 2);
        mm3(waB, zb);
    }
    __builtin_amdgcn_s_setprio(0);
    __syncthreads();   // all waves done reading Z1

    // ---- Z2 scatter (packed): lane holds rows n=B*16+quad*4+{0..3} of col m ----
    // Z2[m][n] -> A-frag slot: ks=n>>5, sub-lane hi=(n&31)>>3, j=n&7.
#pragma unroll
    for (int i = 0; i < 3; ++i) {
        if (i < cnt1) {
            int B = base1 + i;                       // ntile 0..19
            const floatx4 bb = *(const floatx4*)(b2p + B * 16 + quad * 4);
            half2v hb0 = pkrtz(bb[0], bb[1]);
            half2v hb1 = pkrtz(bb[2], bb[3]);
            int ks = B >> 1;
            int khi = (2 * B + (quad >> 1)) & 3;
            int jo = (quad & 1) * 4;
#pragma unroll
            for (int mt = 0; mt < 4; ++mt) {
                half2v c01 = pkrtz(c1[i][mt][0], c1[i][mt][1]);
                half2v c23 = pkrtz(c1[i][mt][2], c1[i][mt][3]);
                union { half2v h[2]; unsigned long long ll; } o;
                o.h[0] = __builtin_elementwise_max(c01 + hb0, hzero);
                o.h[1] = __builtin_elementwise_max(c23 + hb1, hzero);
                *(unsigned long long*)(Zs + ((mt * KS1 + ks) * 64 + l15 + 16 * khi) * 8 + jo) = o.ll;
            }
        }
    }

    // ---- GEMM2 first weight fragment hoisted above the barrier ----
    const unsigned short* pb3 = PB3 + ((size_t)w * KS2 * 64 + lane) * 8;
    half8 bA, bB;
    if (w < NT2) bA = *(const half8*)(pb3);
    __syncthreads();

    // ---- GEMM2: wave w<7 owns ntile w, all 4 mt; b-frag pipelined ----
    floatx4 c2[4];
#pragma unroll
    for (int mt = 0; mt < 4; ++mt) c2[mt] = (floatx4){0.f, 0.f, 0.f, 0.f};
    if (w < NT2) {
        __builtin_amdgcn_s_setprio(1);
#pragma unroll 1
        for (int ks = 0; ks < KS2; ks += 2) {
            half8 a[4];
#pragma unroll
            for (int mt = 0; mt < 4; ++mt)
                a[mt] = *(const half8*)(Zs + ((mt * KS2 + ks) * 64 + lane) * 8);
            bB = *(const half8*)(pb3 + (ks + 1) * 512);
#pragma unroll
            for (int mt = 0; mt < 4; ++mt)
                c2[mt] = __builtin_amdgcn_mfma_f32_16x16x32_f16(a[mt], bA, c2[mt], 0, 0, 0);
#pragma unroll
            for (int mt = 0; mt < 4; ++mt)
                a[mt] = *(const half8*)(Zs + ((mt * KS2 + ks + 1) * 64 + lane) * 8);
            if (ks + 2 < KS2) bA = *(const half8*)(pb3 + (ks + 2) * 512);
#pragma unroll
            for (int mt = 0; mt < 4; ++mt)
                c2[mt] = __builtin_amdgcn_mfma_f32_16x16x32_f16(a[mt], bB, c2[mt], 0, 0, 0);
        }
        __builtin_amdgcn_s_setprio(0);
    }

    // ---- epilogue: max over 16 edge rows, +b3, relu ----
    if constexpr (OUT_HALF) {
#pragma unroll
        for (int mt = 0; mt < 4; ++mt) {
            int node = node0 + mt;
            if (w < NT2) {
                int col = w * 16 + l15;
                floatx4 a = c2[mt];
                float mx = fmaxf(fmaxf(a[0], a[1]), fmaxf(a[2], a[3]));
                mx = fmaxf(mx, __shfl_xor(mx, 16, 64));
                mx = fmaxf(mx, __shfl_xor(mx, 32, 64));
                if (quad == 0) {
                    unsigned short val = 0;
                    if (col < LDIM) val = f2h(fmaxf(mx + b3[col], 0.f));
                    ((unsigned short*)hout)[(size_t)node * H0W + col] = val;
                }
            }
            if (w == 7 && quad == 0)     // pad cols 112..127
                ((unsigned short*)hout)[(size_t)node * H0W + 112 + l15] = 0;
        }
    } else {
        // fused graph pooling into 25-slice partials
        float* partf = (float*)hout;
        if (w < NT2) {
            int col = w * 16 + l15;
            float bv = (col < LDIM) ? b3[col] : 0.f;
            float s4 = 0.f, m4 = 0.f;
#pragma unroll
            for (int mt = 0; mt < 4; ++mt) {
                floatx4 a = c2[mt];
                float mx = fmaxf(fmaxf(a[0], a[1]), fmaxf(a[2], a[3]));
                mx = fmaxf(mx, __shfl_xor(mx, 16, 64));
                mx = fmaxf(mx, __shfl_xor(mx, 32, 64));
                float v = fmaxf(mx + bv, 0.f);
                s4 += v;
                m4 = fmaxf(m4, v);
            }
            if (quad == 0 && col < LDIM) {
                int slice = blockIdx.x >> 5;          // = g*25 + sl  (32 blocks/slice)
                float* ps = partf + (size_t)slice * 200;
                atomicAdd(ps + col, s4);
                atomicMax((int*)(ps + 100 + col), __float_as_int(m4));
            }
        }

        // ---- last-block fused head MLP, CHEAP release fence ----
        // Atomics are performed at the device coherence point (not write-back
        // cached locally), so completion (vmcnt=0) IS the release; no wbl2.
        asm volatile("s_waitcnt vmcnt(0)" ::: "memory");
        __syncthreads();                          // whole block's atomics performed
        if (t == 0) lastFlag = (atomicAdd(counter, 1) == (NNODES / 4 - 1));
        __syncthreads();
        if (lastFlag) {
            __threadfence();                      // acquire: once, winner block only
            float* P  = (float*)Zs;               // [8][300] fp32 scratch in LDS
            float* T1 = P + BGRAPHS * 300;        // [8][100]
            float* T2 = T1 + BGRAPHS * 100;       // [8][100]  (total 16 KB < 40 KB)
            for (int i = t; i < BGRAPHS * LDIM; i += 512) {
                int gg = i / LDIM, f = i - (i / LDIM) * LDIM;
                float s = 0.f, mx = 0.f;
                for (int sl = 0; sl < 25; ++sl) {
                    s += partf[(size_t)(gg * 25 + sl) * 200 + f];
                    mx = fmaxf(mx, partf[(size_t)(gg * 25 + sl) * 200 + 100 + f]);
                }
                P[gg * 300 + f] = s;
                P[gg * 300 + LDIM + f] = s * (1.0f / NPG);
                P[gg * 300 + 2 * LDIM + f] = mx;
            }
            __syncthreads();
            for (int i = t; i < BGRAPHS * LDIM; i += 512) {
                int gg = i / LDIM, c = i - (i / LDIM) * LDIM;
                float a = lb1[c];
                for (int k = 0; k < 3 * LDIM; ++k) a = fmaf(P[gg * 300 + k], lW1[k * LDIM + c], a);
                T1[gg * 100 + c] = fmaxf(a, 0.f);
            }
            __syncthreads();
            for (int i = t; i < BGRAPHS * LDIM; i += 512) {
                int gg = i / LDIM, c = i - (i / LDIM) * LDIM;
                float a = lb2[c];
                for (int k = 0; k < LDIM; ++k) a = fmaf(T1[gg * 100 + k], lW2[k * LDIM + c], a);
                T2[gg * 100 + c] = fmaxf(a, 0.f);
            }
            __syncthreads();
            if (t < BGRAPHS) {
                float a = lb3[0];
                for (int k = 0; k < LDIM; ++k) a = fmaf(T2[t * 100 + k], lW3[k], a);
                out[t] = a;
            }
        }
    }
}

// ---------------------------------------------------------------------------
extern "C" void kernel_launch(void* const* d_in, const int* in_sizes, int n_in,
                              void* d_out, int out_size, void* d_ws, size_t ws_size,
                              hipStream_t stream)
{
    const float* x      = (const float*)d_in[0];
    const int*   src    = (const int*)d_in[1];
    const float* l0_W1  = (const float*)d_in[3];
    const float* l0_b1  = (const float*)d_in[4];
    const float* l0_W2  = (const float*)d_in[5];
    const float* l0_b2  = (const float*)d_in[6];
    const float* l0_W3  = (const float*)d_in[7];
    const float* l0_b3  = (const float*)d_in[8];
    const float* l1_W1  = (const float*)d_in[9];
    const float* l1_b1  = (const float*)d_in[10];
    const float* l1_W2  = (const float*)d_in[11];
    const float* l1_b2  = (const float*)d_in[12];
    const float* l1_W3  = (const float*)d_in[13];
    const float* l1_b3  = (const float*)d_in[14];
    const float* lin_W1 = (const float*)d_in[15];
    const float* lin_b1 = (const float*)d_in[16];
    const float* lin_W2 = (const float*)d_in[17];
    const float* lin_b2 = (const float*)d_in[18];
    const float* lin_W3 = (const float*)d_in[19];
    const float* lin_b3 = (const float*)d_in[20];
    float* out = (float*)d_out;

    char* p = (char*)d_ws;
    unsigned short* Ubuf  = (unsigned short*)p;  p += (size_t)NNODES * HP * 2;      // 16.38 MB
    unsigned short* Vbuf  = (unsigned short*)p;  p += (size_t)NNODES * HP * 2;      // 16.38 MB
    unsigned short* h0b   = (unsigned short*)p;  p += (size_t)NNODES * H0W * 2;     // 6.55 MB
    unsigned short* PB2_0 = (unsigned short*)p;  p += (size_t)S0 * 2;
    unsigned short* PB2_1 = (unsigned short*)p;  p += (size_t)S1 * 2;
    unsigned short* PB3_0 = (unsigned short*)p;  p += (size_t)S2 * 2;
    unsigned short* PB3_1 = (unsigned short*)p;  p += (size_t)S3 * 2;
    unsigned short* PW1   = (unsigned short*)p;  p += (size_t)S4 * 2;
    unsigned short* PW0   = (unsigned short*)p;  p += (size_t)S5 * 2;
    float* b2p_0          = (float*)p;           p += HP * 4;
    float* b2p_1          = (float*)p;           p += HP * 4;
    float* bp1            = (float*)p;           p += 640 * 4;
    float* bp0            = (float*)p;           p += 640 * 4;
    float* part           = (float*)p;           p += (size_t)40004 * 4;            // partials + counter
    int* counter          = (int*)(part + 40000);

    pack_all_kernel<<<(PACK_TOTAL + 255) / 256, 256, 0, stream>>>(
        l0_W1, l0_b1, l0_W2, l0_b2, l0_W3,
        l1_W1, l1_b1, l1_W2, l1_b2, l1_W3,
        PB2_0, PB2_1, PB3_0, PB3_1, PW1, PW0, b2p_0, b2p_1, bp1, bp0, part);

    // layer 0
    proj_gemm_kernel<1, true><<<NNODES / 32, 256, 0, stream>>>(x, PW0, bp0, Ubuf, Vbuf);
    edge_mfma_kernel<true><<<NNODES / 4, 512, 0, stream>>>(
        Ubuf, Vbuf, src, PB2_0, b2p_0, PB3_0, l0_b3, h0b,
        nullptr, nullptr, nullptr, nullptr, nullptr, nullptr, nullptr, nullptr);
    // layer 1 (pooling fused via slice atomics; last block runs the head MLP)
    proj_gemm_kernel<4, false><<<NNODES / 32, 256, 0, stream>>>(h0b, PW1, bp1, Ubuf, Vbuf);
    edge_mfma_kernel<false><<<NNODES / 4, 512, 0, stream>>>(
        Ubuf, Vbuf, src, PB2_1, b2p_1, PB3_1, l1_b3, part,
        counter, lin_W1, lin_b1, lin_W2, lin_b2, lin_W3, lin_b3, out);
}

// Round 13
// 390.573 us; speedup vs baseline: 3.7195x; 1.0224x over previous
//
#include <hip/hip_runtime.h>

#define NNODES 25600
#define DEG 16
#define BGRAPHS 8
#define NPG (NNODES / BGRAPHS)   // 3200
#define FDIM 7
#define HDIM 300
#define LDIM 100
#define HP 320                   // padded H
#define NT1 20                   // GEMM1 N tiles
#define KS1 10                   // GEMM1 K steps
#define NT2 7                    // GEMM2 N tiles (112 cols, >=100 masked)
#define KS2 10                   // GEMM2 K steps
#define H0W 128                  // h0 fp16 padded width
#define SSTR 328                 // proj staging row stride (shorts)

typedef __attribute__((ext_vector_type(8))) _Float16 half8;
typedef __attribute__((ext_vector_type(2))) _Float16 half2v;
typedef __attribute__((ext_vector_type(4))) float floatx4;

__device__ __forceinline__ unsigned short f2h(float f) {   // fp32 -> fp16 bits (RNE)
    _Float16 h = (_Float16)f;
    return __builtin_bit_cast(unsigned short, h);
}

// packed fp32x2 -> fp16x2 (RTZ), re-typed to half2v
__device__ __forceinline__ half2v pkrtz(float a, float b) {
    return __builtin_bit_cast(half2v, __builtin_amdgcn_cvt_pkrtz(a, b));
}

union UV4H { uint4 v; half2v h[4]; };

// ---------------------------------------------------------------------------
// B-fragment packing, 4 consecutive j per thread (one 8B store):
// out[((nt*KS+ks)*64+lane)*8+j] = W[k][n]
// ---------------------------------------------------------------------------
__device__ __forceinline__ unsigned long long packB4(const float* W, int Kreal,
                                                     int Nreal, int KS, int rel)
{
    int j0 = rel & 7, lane = (rel >> 3) & 63, rem = rel >> 9;
    int ks = rem % KS, nt = rem / KS;
    int kb = ks * 32 + ((lane >> 4) << 3) + j0;
    int n = nt * 16 + (lane & 15);
    union { unsigned short us[4]; unsigned long long ll; } o;
#pragma unroll
    for (int j = 0; j < 4; ++j) {
        int k = kb + j;
        o.us[j] = (k < Kreal && n < Nreal) ? f2h(W[k * Nreal + n]) : (unsigned short)0;
    }
    return o.ll;
}

// proj effective weights Weff[k][n], n<320 = U part (W1a - W1b), n>=320 = V part
__device__ __forceinline__ unsigned long long packProjW4(const float* W1, int Ksub,
                                                         int KS, int rel)
{
    int j0 = rel & 7, lane = (rel >> 3) & 63, rem = rel >> 9;
    int ks = rem % KS, nt = rem / KS;
    int kb = ks * 32 + ((lane >> 4) << 3) + j0;
    int n = nt * 16 + (lane & 15);
    union { unsigned short us[4]; unsigned long long ll; } o;
#pragma unroll
    for (int j = 0; j < 4; ++j) {
        int k = kb + j;
        float v = 0.f;
        if (k < Ksub) {
            if (n < HP) { if (n < HDIM) v = W1[k * HDIM + n] - W1[(k + Ksub) * HDIM + n]; }
            else { int m = n - HP; if (m < HDIM) v = W1[(k + Ksub) * HDIM + m]; }
        }
        o.us[j] = f2h(v);
    }
    return o.ll;
}

#define S0 102400   // PB2_0
#define S1 102400   // PB2_1
#define S2 35840    // PB3_0
#define S3 35840    // PB3_1
#define S4 81920    // PW1 (40 nt x 4 ks)
#define S5 20480    // PW0 (40 nt x 1 ks)
// vectorized (4 shorts / thread) segment sizes:
#define P0 (S0/4)
#define P1 (S1/4)
#define P2 (S2/4)
#define P3 (S3/4)
#define P4 (S4/4)
#define P5 (S5/4)
#define PV (P0+P1+P2+P3+P4+P5)   // 94720
#define PBIAS 1920
#define PZERO 10001              // 40004 part floats (incl. done-counter) as float4
#define PACK_TOTAL (PV+PBIAS+PZERO)

__global__ __launch_bounds__(256) void pack_all_kernel(
    const float* __restrict__ l0_W1, const float* __restrict__ l0_b1,
    const float* __restrict__ l0_W2, const float* __restrict__ l0_b2,
    const float* __restrict__ l0_W3,
    const float* __restrict__ l1_W1, const float* __restrict__ l1_b1,
    const float* __restrict__ l1_W2, const float* __restrict__ l1_b2,
    const float* __restrict__ l1_W3,
    unsigned short* __restrict__ PB2_0, unsigned short* __restrict__ PB2_1,
    unsigned short* __restrict__ PB3_0, unsigned short* __restrict__ PB3_1,
    unsigned short* __restrict__ PW1,  unsigned short* __restrict__ PW0,
    float* __restrict__ b2p_0, float* __restrict__ b2p_1,
    float* __restrict__ bp1,   float* __restrict__ bp0,
    float* __restrict__ part)
{
    int idx = blockIdx.x * 256 + threadIdx.x;
    if (idx >= PACK_TOTAL) return;
    if (idx < P0) { ((unsigned long long*)PB2_0)[idx] = packB4(l0_W2, HDIM, HDIM, KS1, idx * 4); return; }
    idx -= P0;
    if (idx < P1) { ((unsigned long long*)PB2_1)[idx] = packB4(l1_W2, HDIM, HDIM, KS1, idx * 4); return; }
    idx -= P1;
    if (idx < P2) { ((unsigned long long*)PB3_0)[idx] = packB4(l0_W3, HDIM, LDIM, KS2, idx * 4); return; }
    idx -= P2;
    if (idx < P3) { ((unsigned long long*)PB3_1)[idx] = packB4(l1_W3, HDIM, LDIM, KS2, idx * 4); return; }
    idx -= P3;
    if (idx < P4) { ((unsigned long long*)PW1)[idx] = packProjW4(l1_W1, LDIM, 4, idx * 4); return; }
    idx -= P4;
    if (idx < P5) { ((unsigned long long*)PW0)[idx] = packProjW4(l0_W1, FDIM, 1, idx * 4); return; }
    idx -= P5;
    if (idx < 320)       { b2p_0[idx] = (idx < HDIM) ? l0_b2[idx] : 0.f; return; }
    if (idx < 640)       { int n = idx - 320; b2p_1[n] = (n < HDIM) ? l1_b2[n] : 0.f; return; }
    if (idx < 1280)      { int n = idx - 640; bp1[n] = (n < HDIM) ? l1_b1[n] : 0.f; return; }
    if (idx < 1920)      { int n = idx - 1280; bp0[n] = (n < HDIM) ? l0_b1[n] : 0.f; return; }
    ((floatx4*)part)[idx - 1920] = (floatx4){0.f, 0.f, 0.f, 0.f};   // re-zero partials + counter
}

// ---------------------------------------------------------------------------
// proj GEMM: A[64 rows] x Weff[K,320-col group] -> U or V fp16 (bias, no relu).
// Grid = 800: block handles (row strip = bid>>1, group g = bid&1). 2 barriers.
// ---------------------------------------------------------------------------
template<int KS, bool A_IS_X>
__global__ __launch_bounds__(256) void proj_gemm_kernel(
    const void* __restrict__ Asrc, const unsigned short* __restrict__ PW,
    const float* __restrict__ bp,
    unsigned short* __restrict__ Ub, unsigned short* __restrict__ Vb)
{
    __shared__ unsigned short As[4 * KS * 64 * 8];
    __shared__ unsigned short S[64 * SSTR];
    const int t = threadIdx.x;
    const int g = blockIdx.x & 1;
    const int row0 = (blockIdx.x >> 1) * 64;

    if constexpr (A_IS_X) {
        const float* x = (const float*)Asrc;
        int lane = t & 63, mt = t >> 6;
        int quad = lane >> 4;
        int grow = row0 + mt * 16 + (lane & 15);
        unsigned short oz[8];
#pragma unroll
        for (int j = 0; j < 8; ++j) {
            int k = quad * 8 + j;
            oz[j] = (k < FDIM) ? f2h(x[grow * FDIM + k]) : (unsigned short)0;
        }
        *(uint4*)(As + t * 8) = *(uint4*)oz;
    } else {
        const unsigned short* h = (const unsigned short*)Asrc;
#pragma unroll
        for (int i = 0; i < 4; ++i) {
            int s = t + 256 * i;
            int lane = s & 63;
            int ks = (s >> 6) % KS;
            int mt = s / (KS * 64);
            int grow = row0 + mt * 16 + (lane & 15);
            int k0 = ks * 32 + ((lane >> 4) << 3);
            *(uint4*)(As + s * 8) = *(const uint4*)(h + (size_t)grow * H0W + k0);
        }
    }
    __syncthreads();

    const int w = t >> 6, lane = t & 63, quad = lane >> 4, l15 = lane & 15;
    const int ntb = g * 20 + w * 5;

    floatx4 c[5][4];
#pragma unroll
    for (int i = 0; i < 5; ++i)
#pragma unroll
        for (int mt = 0; mt < 4; ++mt) c[i][mt] = (floatx4){0.f, 0.f, 0.f, 0.f};
#pragma unroll
    for (int ks = 0; ks < KS; ++ks) {
        half8 a[4];
#pragma unroll
        for (int mt = 0; mt < 4; ++mt)
            a[mt] = *(const half8*)(As + ((mt * KS + ks) * 64 + lane) * 8);
#pragma unroll
        for (int i = 0; i < 5; ++i) {
            half8 b = *(const half8*)(PW + (size_t)(((ntb + i) * KS + ks) * 64 + lane) * 8);
#pragma unroll
            for (int mt = 0; mt < 4; ++mt)
                c[i][mt] = __builtin_amdgcn_mfma_f32_16x16x32_f16(a[mt], b, c[i][mt], 0, 0, 0);
        }
    }
#pragma unroll
    for (int i = 0; i < 5; ++i) {
        int colp = (w * 5 + i) * 16 + l15;        // 0..319 group-local
        float bb = bp[g * 320 + colp];
#pragma unroll
        for (int mt = 0; mt < 4; ++mt) {
#pragma unroll
            for (int r = 0; r < 4; ++r) {
                int row = mt * 16 + quad * 4 + r;
                S[row * SSTR + colp] = f2h(c[i][mt][r] + bb);
            }
        }
    }
    __syncthreads();
    unsigned short* dst = g ? Vb : Ub;
#pragma unroll
    for (int it = 0; it < 10; ++it) {
        int s = t + 256 * it;
        int row = s / 40, c4 = s - row * 40;
        uint4 v = *(const uint4*)(S + row * SSTR + c4 * 8);
        *(uint4*)(dst + (size_t)(row0 + row) * HP + c4 * 8) = v;
    }
}

// ---------------------------------------------------------------------------
// Fused edge MLP + segment-max. Block = 4 nodes (M=64), 512 threads / 8 waves.
// fp16 pipeline. Single 40 KB LDS buffer (EXACTLY 40960 B - the 4-blocks/CU
// LDS cliff; r12 lesson: +4 B static LDS -> 41472 granule -> 3 blocks/CU,
// edges +28%. The last-block flag lives INSIDE Zs dead space, not its own
// __shared__). 3 barriers.
//   Z1 build, remapped: thread (w,lane) owns mt=w>>1 (const), ks=(w&1)*5+q.
//   GEMM1 (operand-swapped), 20 tiles {3,3,3,3,2,2,2,2}; weight frags
//     software-pipelined (ping-pong, distance 1; first frag hoisted above
//     the Z1 barrier).
//   GEMM2: wave w<7 owns 1 ntile; same b-frag pipeline.
//   OUT_HALF=true : store h0 rows (fp16, padded to 128).
//   OUT_HALF=false: fused graph pooling -> slice atomics; LAST block runs the
//     head MLP in-kernel. Cheap fences (r11): release = s_waitcnt vmcnt(0)
//     (atomics performed at device coherence point); acquire = one full
//     __threadfence in the single winning block.
// ---------------------------------------------------------------------------
template<bool OUT_HALF>
__global__ __launch_bounds__(512, 4) void edge_mfma_kernel(
    const unsigned short* __restrict__ Ub,
    const unsigned short* __restrict__ Vb,
    const int* __restrict__ src,
    const unsigned short* __restrict__ PB2, const float* __restrict__ b2p,
    const unsigned short* __restrict__ PB3, const float* __restrict__ b3,
    void* __restrict__ hout,
    int* counter,
    const float* __restrict__ lW1, const float* __restrict__ lb1,
    const float* __restrict__ lW2, const float* __restrict__ lb2,
    const float* __restrict__ lW3, const float* __restrict__ lb3,
    float* __restrict__ out)
{
    __shared__ unsigned short Zs[4 * KS1 * 64 * 8];   // 40960 B exactly

    const int t = threadIdx.x;
    const int node0 = blockIdx.x * 4;
    const int lane = t & 63;
    const int w = t >> 6;                 // 0..7
    const int quad = lane >> 4;
    const int l15 = lane & 15;
    const int slane = lane ^ ((lane & 0x30) >> 3);   // sigma(lane) for Z1 reads

    // Z1-build lane mapping (64B-coalesced gather + swizzled LDS dest)
    const int row16 = lane >> 2;          // 0..15
    const int part  = lane & 3;           // 0..3
    const int fl    = row16 + 16 * part;  // A-frag lane
    const int phys  = fl ^ (part << 1);   // sigma(fl)

    const half2v hzero = {(_Float16)0.f, (_Float16)0.f};

    // ---- Z1 build: thread (w,lane) -> mt=w>>1, ks=(w&1)*5+q, q=0..4 ----
    {
        const int mtw = w >> 1;
        const int ks0 = (w & 1) * 5;
        const int srcn = src[node0 * 16 + mtw * 16 + row16];
        const unsigned short* up = Ub + (size_t)(node0 + mtw) * HP + ks0 * 32 + part * 8;
        const unsigned short* vp = Vb + (size_t)srcn * HP + ks0 * 32 + part * 8;
        unsigned short* zp = Zs + ((mtw * KS1 + ks0) * 64 + phys) * 8;
#pragma unroll
        for (int q = 0; q < 5; ++q) {
            UV4H ud, vd, o;
            ud.v = *(const uint4*)(up + q * 32);
            vd.v = *(const uint4*)(vp + q * 32);
#pragma unroll
            for (int d = 0; d < 4; ++d) {
                half2v s2 = ud.h[d] + vd.h[d];                       // v_pk_add_f16
                o.h[d] = __builtin_elementwise_max(s2, hzero);       // v_pk_max_f16
            }
            *(uint4*)(zp + q * 512) = o.v;
        }
    }

    // ---- GEMM1 setup + first weight fragment hoisted above the barrier ----
    const int cnt1  = (w < 4) ? 3 : 2;
    const int base1 = (w < 4) ? 3 * w : 12 + 2 * (w - 4);
    const unsigned short* pb = PB2 + ((size_t)base1 * KS1 * 64 + lane) * 8;
    // strides in shorts: ks slab = 512, tile = KS1*512

    auto ld_wa = [&](half8 (&buf)[3], int kss) {
        buf[0] = *(const half8*)(pb + kss * 512);
        buf[1] = *(const half8*)(pb + KS1 * 512 + kss * 512);
        if (cnt1 > 2) buf[2] = *(const half8*)(pb + 2 * KS1 * 512 + kss * 512);
    };
    auto ld_zb = [&](half8 (&zb)[4], int ks) {
#pragma unroll
        for (int mt = 0; mt < 4; ++mt)
            zb[mt] = *(const half8*)(Zs + ((mt * KS1 + ks) * 64 + slane) * 8);
    };

    floatx4 c1[3][4];
#pragma unroll
    for (int i = 0; i < 3; ++i)
#pragma unroll
        for (int mt = 0; mt < 4; ++mt) c1[i][mt] = (floatx4){0.f, 0.f, 0.f, 0.f};

    auto mm3 = [&](half8 (&wa)[3], half8 (&zb)[4]) {
#pragma unroll
        for (int i = 0; i < 3; ++i) {
            if (i < cnt1) {
#pragma unroll
                for (int mt = 0; mt < 4; ++mt)
                    c1[i][mt] = __builtin_amdgcn_mfma_f32_16x16x32_f16(wa[i], zb[mt], c1[i][mt], 0, 0, 0);
            }
        }
    };

    half8 waA[3], waB[3];
    ld_wa(waA, 0);                 // overlaps the Z1 gather (read-only global)
    __syncthreads();

    // ---- GEMM1: ping-pong prefetch, distance 1, elevated priority ----
    __builtin_amdgcn_s_setprio(1);
#pragma unroll 1
    for (int ks = 0; ks < KS1; ks += 2) {
        half8 zb[4];
        ld_zb(zb, ks);
        ld_wa(waB, ks + 1);        // ks+1 <= KS1-1 (KS1 even)
        mm3(waA, zb);
        ld_zb(zb, ks + 1);
        if (ks + 2 < KS1) ld_wa(waA, ks + 2);
        mm3(waB, zb);
    }
    __builtin_amdgcn_s_setprio(0);
    __syncthreads();   // all waves done reading Z1

    // ---- Z2 scatter (packed): lane holds rows n=B*16+quad*4+{0..3} of col m ----
    // Z2[m][n] -> A-frag slot: ks=n>>5, sub-lane hi=(n&31)>>3, j=n&7.
#pragma unroll
    for (int i = 0; i < 3; ++i) {
        if (i < cnt1) {
            int B = base1 + i;                       // ntile 0..19
            const floatx4 bb = *(const floatx4*)(b2p + B * 16 + quad * 4);
            half2v hb0 = pkrtz(bb[0], bb[1]);
            half2v hb1 = pkrtz(bb[2], bb[3]);
            int ks = B >> 1;
            int khi = (2 * B + (quad >> 1)) & 3;
            int jo = (quad & 1) * 4;
#pragma unroll
            for (int mt = 0; mt < 4; ++mt) {
                half2v c01 = pkrtz(c1[i][mt][0], c1[i][mt][1]);
                half2v c23 = pkrtz(c1[i][mt][2], c1[i][mt][3]);
                union { half2v h[2]; unsigned long long ll; } o;
                o.h[0] = __builtin_elementwise_max(c01 + hb0, hzero);
                o.h[1] = __builtin_elementwise_max(c23 + hb1, hzero);
                *(unsigned long long*)(Zs + ((mt * KS1 + ks) * 64 + l15 + 16 * khi) * 8 + jo) = o.ll;
            }
        }
    }

    // ---- GEMM2 first weight fragment hoisted above the barrier ----
    const unsigned short* pb3 = PB3 + ((size_t)w * KS2 * 64 + lane) * 8;
    half8 bA, bB;
    if (w < NT2) bA = *(const half8*)(pb3);
    __syncthreads();

    // ---- GEMM2: wave w<7 owns ntile w, all 4 mt; b-frag pipelined ----
    floatx4 c2[4];
#pragma unroll
    for (int mt = 0; mt < 4; ++mt) c2[mt] = (floatx4){0.f, 0.f, 0.f, 0.f};
    if (w < NT2) {
        __builtin_amdgcn_s_setprio(1);
#pragma unroll 1
        for (int ks = 0; ks < KS2; ks += 2) {
            half8 a[4];
#pragma unroll
            for (int mt = 0; mt < 4; ++mt)
                a[mt] = *(const half8*)(Zs + ((mt * KS2 + ks) * 64 + lane) * 8);
            bB = *(const half8*)(pb3 + (ks + 1) * 512);
#pragma unroll
            for (int mt = 0; mt < 4; ++mt)
                c2[mt] = __builtin_amdgcn_mfma_f32_16x16x32_f16(a[mt], bA, c2[mt], 0, 0, 0);
#pragma unroll
            for (int mt = 0; mt < 4; ++mt)
                a[mt] = *(const half8*)(Zs + ((mt * KS2 + ks + 1) * 64 + lane) * 8);
            if (ks + 2 < KS2) bA = *(const half8*)(pb3 + (ks + 2) * 512);
#pragma unroll
            for (int mt = 0; mt < 4; ++mt)
                c2[mt] = __builtin_amdgcn_mfma_f32_16x16x32_f16(a[mt], bB, c2[mt], 0, 0, 0);
        }
        __builtin_amdgcn_s_setprio(0);
    }

    // ---- epilogue: max over 16 edge rows, +b3, relu ----
    if constexpr (OUT_HALF) {
#pragma unroll
        for (int mt = 0; mt < 4; ++mt) {
            int node = node0 + mt;
            if (w < NT2) {
                int col = w * 16 + l15;
                floatx4 a = c2[mt];
                float mx = fmaxf(fmaxf(a[0], a[1]), fmaxf(a[2], a[3]));
                mx = fmaxf(mx, __shfl_xor(mx, 16, 64));
                mx = fmaxf(mx, __shfl_xor(mx, 32, 64));
                if (quad == 0) {
                    unsigned short val = 0;
                    if (col < LDIM) val = f2h(fmaxf(mx + b3[col], 0.f));
                    ((unsigned short*)hout)[(size_t)node * H0W + col] = val;
                }
            }
            if (w == 7 && quad == 0)     // pad cols 112..127
                ((unsigned short*)hout)[(size_t)node * H0W + 112 + l15] = 0;
        }
    } else {
        // fused graph pooling into 25-slice partials
        float* partf = (float*)hout;
        if (w < NT2) {
            int col = w * 16 + l15;
            float bv = (col < LDIM) ? b3[col] : 0.f;
            float s4 = 0.f, m4 = 0.f;
#pragma unroll
            for (int mt = 0; mt < 4; ++mt) {
                floatx4 a = c2[mt];
                float mx = fmaxf(fmaxf(a[0], a[1]), fmaxf(a[2], a[3]));
                mx = fmaxf(mx, __shfl_xor(mx, 16, 64));
                mx = fmaxf(mx, __shfl_xor(mx, 32, 64));
                float v = fmaxf(mx + bv, 0.f);
                s4 += v;
                m4 = fmaxf(m4, v);
            }
            if (quad == 0 && col < LDIM) {
                int slice = blockIdx.x >> 5;          // = g*25 + sl  (32 blocks/slice)
                float* ps = partf + (size_t)slice * 200;
                atomicAdd(ps + col, s4);
                atomicMax((int*)(ps + 100 + col), __float_as_int(m4));
            }
        }

        // ---- last-block fused head MLP; flag lives in Zs dead space ----
        // Release: atomics are performed at the device coherence point, so
        // vmcnt(0) IS the release (no wbl2 - r11 lesson). Zs reads (GEMM2)
        // are also complete before the barrier below.
        int* flagp = (int*)(Zs + 20000);          // byte offset 40000, past scratch
        asm volatile("s_waitcnt vmcnt(0)" ::: "memory");
        __syncthreads();                          // block's atomics + Zs reads done
        if (t == 0) *flagp = (atomicAdd(counter, 1) == (NNODES / 4 - 1));
        __syncthreads();
        if (*flagp) {
            __threadfence();                      // acquire: once, winner block only
            float* P  = (float*)Zs;               // [8][300] fp32 scratch in LDS
            float* T1 = P + BGRAPHS * 300;        // [8][100]
            float* T2 = T1 + BGRAPHS * 100;       // [8][100]  (16000 B < 40000)
            for (int i = t; i < BGRAPHS * LDIM; i += 512) {
                int gg = i / LDIM, f = i - (i / LDIM) * LDIM;
                float s = 0.f, mx = 0.f;
                for (int sl = 0; sl < 25; ++sl) {
                    s += partf[(size_t)(gg * 25 + sl) * 200 + f];
                    mx = fmaxf(mx, partf[(size_t)(gg * 25 + sl) * 200 + 100 + f]);
                }
                P[gg * 300 + f] = s;
                P[gg * 300 + LDIM + f] = s * (1.0f / NPG);
                P[gg * 300 + 2 * LDIM + f] = mx;
            }
            __syncthreads();
            for (int i = t; i < BGRAPHS * LDIM; i += 512) {
                int gg = i / LDIM, c = i - (i / LDIM) * LDIM;
                float a = lb1[c];
                for (int k = 0; k < 3 * LDIM; ++k) a = fmaf(P[gg * 300 + k], lW1[k * LDIM + c], a);
                T1[gg * 100 + c] = fmaxf(a, 0.f);
            }
            __syncthreads();
            for (int i = t; i < BGRAPHS * LDIM; i += 512) {
                int gg = i / LDIM, c = i - (i / LDIM) * LDIM;
                float a = lb2[c];
                for (int k = 0; k < LDIM; ++k) a = fmaf(T1[gg * 100 + k], lW2[k * LDIM + c], a);
                T2[gg * 100 + c] = fmaxf(a, 0.f);
            }
            __syncthreads();
            if (t < BGRAPHS) {
                float a = lb3[0];
                for (int k = 0; k < LDIM; ++k) a = fmaf(T2[t * 100 + k], lW3[k], a);
                out[t] = a;
            }
        }
    }
}

// ---------------------------------------------------------------------------
extern "C" void kernel_launch(void* const* d_in, const int* in_sizes, int n_in,
                              void* d_out, int out_size, void* d_ws, size_t ws_size,
                              hipStream_t stream)
{
    const float* x      = (const float*)d_in[0];
    const int*   src    = (const int*)d_in[1];
    const float* l0_W1  = (const float*)d_in[3];
    const float* l0_b1  = (const float*)d_in[4];
    const float* l0_W2  = (const float*)d_in[5];
    const float* l0_b2  = (const float*)d_in[6];
    const float* l0_W3  = (const float*)d_in[7];
    const float* l0_b3  = (const float*)d_in[8];
    const float* l1_W1  = (const float*)d_in[9];
    const float* l1_b1  = (const float*)d_in[10];
    const float* l1_W2  = (const float*)d_in[11];
    const float* l1_b2  = (const float*)d_in[12];
    const float* l1_W3  = (const float*)d_in[13];
    const float* l1_b3  = (const float*)d_in[14];
    const float* lin_W1 = (const float*)d_in[15];
    const float* lin_b1 = (const float*)d_in[16];
    const float* lin_W2 = (const float*)d_in[17];
    const float* lin_b2 = (const float*)d_in[18];
    const float* lin_W3 = (const float*)d_in[19];
    const float* lin_b3 = (const float*)d_in[20];
    float* out = (float*)d_out;

    char* p = (char*)d_ws;
    unsigned short* Ubuf  = (unsigned short*)p;  p += (size_t)NNODES * HP * 2;      // 16.38 MB
    unsigned short* Vbuf  = (unsigned short*)p;  p += (size_t)NNODES * HP * 2;      // 16.38 MB
    unsigned short* h0b   = (unsigned short*)p;  p += (size_t)NNODES * H0W * 2;     // 6.55 MB
    unsigned short* PB2_0 = (unsigned short*)p;  p += (size_t)S0 * 2;
    unsigned short* PB2_1 = (unsigned short*)p;  p += (size_t)S1 * 2;
    unsigned short* PB3_0 = (unsigned short*)p;  p += (size_t)S2 * 2;
    unsigned short* PB3_1 = (unsigned short*)p;  p += (size_t)S3 * 2;
    unsigned short* PW1   = (unsigned short*)p;  p += (size_t)S4 * 2;
    unsigned short* PW0   = (unsigned short*)p;  p += (size_t)S5 * 2;
    float* b2p_0          = (float*)p;           p += HP * 4;
    float* b2p_1          = (float*)p;           p += HP * 4;
    float* bp1            = (float*)p;           p += 640 * 4;
    float* bp0            = (float*)p;           p += 640 * 4;
    float* part           = (float*)p;           p += (size_t)40004 * 4;            // partials + counter
    int* counter          = (int*)(part + 40000);

    pack_all_kernel<<<(PACK_TOTAL + 255) / 256, 256, 0, stream>>>(
        l0_W1, l0_b1, l0_W2, l0_b2, l0_W3,
        l1_W1, l1_b1, l1_W2, l1_b2, l1_W3,
        PB2_0, PB2_1, PB3_0, PB3_1, PW1, PW0, b2p_0, b2p_1, bp1, bp0, part);

    // layer 0
    proj_gemm_kernel<1, true><<<NNODES / 32, 256, 0, stream>>>(x, PW0, bp0, Ubuf, Vbuf);
    edge_mfma_kernel<true><<<NNODES / 4, 512, 0, stream>>>(
        Ubuf, Vbuf, src, PB2_0, b2p_0, PB3_0, l0_b3, h0b,
        nullptr, nullptr, nullptr, nullptr, nullptr, nullptr, nullptr, nullptr);
    // layer 1 (pooling fused via slice atomics; last block runs the head MLP)
    proj_gemm_kernel<4, false><<<NNODES / 32, 256, 0, stream>>>(h0b, PW1, bp1, Ubuf, Vbuf);
    edge_mfma_kernel<false><<<NNODES / 4, 512, 0, stream>>>(
        Ubuf, Vbuf, src, PB2_1, b2p_1, PB3_1, l1_b3, part,
        counter, lin_W1, lin_b1, lin_W2, lin_b2, lin_W3, lin_b3, out);
}